// Round 2
// baseline (919.031 us; speedup 1.0000x reference)
//
#include <hip/hip_runtime.h>
#include <cstddef>

#define NB   32
#define CH   512
#define HHW  3136      // 56*56
#define HW4  784       // HHW/4
#define FF   8
#define CR   32        // C/R
#define CIT  2         // channels per wave in pool
#define BLKS_PER_N 64  // CH / (4 waves * CIT)

typedef float f4v __attribute__((ext_vector_type(4)));

// ------- Kernel 1: separable DCT pooling + fused last-block excite -------
// Pool: identical to R1 (coalesced separable form, ~BW floor).
// Excite: instead of a separate 32-block kernel (serial bubble + launch gap),
// the LAST pool block to finish each n (device-scope atomicAdd on cnt[n],
// __threadfence release/acquire pair for cross-XCD y visibility) computes
// z = relu(y.w1) into LDS and s = sigmoid(z.w2) for that n.  Excite work
// overlaps the pool drain of other CUs.
__global__ __launch_bounds__(256, 4)
void pool_excite_kernel(const float* __restrict__ x,
                        const float* __restrict__ dct,
                        float* y                     /* (N,F,C)  */,
                        const float* __restrict__ w1 /* (F,CR,C) */,
                        const float* __restrict__ w2 /* (C,F,CR) */,
                        float* s                     /* (N,C)    */,
                        int* cnt                     /* (N)      */) {
    __shared__ float4 bht[60];      // [h] -> {b0,b1,b2,b3}(h); 56..59 zero pad
    __shared__ float4 bwt[14][4];   // [wc][p] -> b_p(4wc..4wc+3)

    const int t = threadIdx.x;
    const float SQ = 7.4833147735478827f;   // sqrt(56): b0(h) == 1/sqrt(56)
    if (t < 56) {
        bht[t] = make_float4(dct[0*HHW + t*56] * SQ,    // b0(h) from f0 (u=0)
                             dct[2*HHW + t*56] * SQ,    // b1(h) from f2 (u=1)
                             dct[7*HHW + t*56] * SQ,    // b2(h) from f7 (u=2)
                             dct[5*HHW + t*56] * SQ);   // b3(h) from f5 (u=3)
    } else if (t < 60) {
        bht[t] = make_float4(0.f, 0.f, 0.f, 0.f);       // pad for idle lanes
    } else if (t >= 64 && t < 120) {
        const int i = t - 64, wc = i >> 2, p = i & 3;
        const int FP[4] = {0, 1, 6, 4};                 // v=0,1,2,3 source filters
        const float4 v = *(const float4*)(dct + (size_t)FP[p]*HHW + wc*4);
        bwt[wc][p] = make_float4(v.x*SQ, v.y*SQ, v.z*SQ, v.w*SQ);
    }
    __syncthreads();

    const int lane = t & 63, wave = t >> 6;
    const int r  = lane / 14;                 // 0..3; 4 for lanes 56..63
    const int wc = lane % 14;
    const int lx = lane < 56 ? lane : 55;     // clamped in-bounds dup load
    const float zf = lane < 56 ? 1.f : 0.f;   // zero idle lanes' contributions
    float4 bw0 = bwt[wc][0], bw1 = bwt[wc][1], bw2 = bwt[wc][2], bw3 = bwt[wc][3];
    bw0.x*=zf; bw0.y*=zf; bw0.z*=zf; bw0.w*=zf;
    bw1.x*=zf; bw1.y*=zf; bw1.z*=zf; bw1.w*=zf;
    bw2.x*=zf; bw2.y*=zf; bw2.z*=zf; bw2.w*=zf;
    bw3.x*=zf; bw3.y*=zf; bw3.z*=zf; bw3.w*=zf;

    const int gc0 = blockIdx.x * (4*CIT) + wave * CIT;  // global channel base
    const int n   = blockIdx.x / BLKS_PER_N;

    for (int it = 0; it < CIT; ++it) {
        const int gc = gc0 + it;                         // n*CH + c
        const float4* xb = (const float4*)(x + (size_t)gc * HHW);
        float acc[8] = {0.f,0.f,0.f,0.f,0.f,0.f,0.f,0.f};
        #pragma unroll
        for (int j = 0; j < 14; ++j) {                   // rows 4j..4j+3
            const float4 xv = xb[j*56 + lx];
            const float4 bh = bht[4*j + r];              // 4-addr multicast
            const float s0 = xv.x*bw0.x + xv.y*bw0.y + xv.z*bw0.z + xv.w*bw0.w;
            const float s1 = xv.x*bw1.x + xv.y*bw1.y + xv.z*bw1.z + xv.w*bw1.w;
            const float s2 = xv.x*bw2.x + xv.y*bw2.y + xv.z*bw2.z + xv.w*bw2.w;
            const float s3 = xv.x*bw3.x + xv.y*bw3.y + xv.z*bw3.z + xv.w*bw3.w;
            acc[0] += bh.x * s0;    // f0: (0,0)
            acc[1] += bh.x * s1;    // f1: (0,1)
            acc[2] += bh.y * s0;    // f2: (1,0)
            acc[3] += bh.y * s1;    // f3: (-1,-1) == (1,1)
            acc[4] += bh.x * s3;    // f4: (0,3)
            acc[5] += bh.w * s0;    // f5: (3,0)
            acc[6] += bh.x * s2;    // f6: (0,2)
            acc[7] += bh.z * s0;    // f7: (2,0)
        }

#define RSTEP(S, HALF)                                              \
        {                                                           \
            const bool hi = (lane >> (S)) & 1;                      \
            _Pragma("unroll")                                       \
            for (int k = 0; k < (HALF); ++k) {                      \
                float send = hi ? acc[k] : acc[k + (HALF)];         \
                float recv = __shfl_xor(send, 1 << (S), 64);        \
                acc[k] = (hi ? acc[k + (HALF)] : acc[k]) + recv;    \
            }                                                       \
        }
        RSTEP(0, 4) RSTEP(1, 2) RSTEP(2, 1)
#undef RSTEP
        acc[0] += __shfl_xor(acc[0], 8, 64);
        acc[0] += __shfl_xor(acc[0], 16, 64);
        acc[0] += __shfl_xor(acc[0], 32, 64);

        if (lane < 8) {
            const int f = ((lane & 1) << 2) | (lane & 2) | ((lane >> 2) & 1);
            y[(size_t)n * (FF*CH) + (size_t)f * CH + (gc & (CH-1))] = acc[0];
        }
    }

    // ---- last-block-done: fused excite for this n ----
    __shared__ int lastFlag;
    __syncthreads();
    __threadfence();                          // release y writes (cross-XCD)
    if (t == 0)
        lastFlag = (atomicAdd(&cnt[n], 1) == BLKS_PER_N - 1);
    __syncthreads();
    if (!lastFlag) return;
    __threadfence();                          // acquire: see all blocks' y

    __shared__ __align__(16) float zl[FF * CR];   // 1 KB
    const int f = t >> 5, o = t & 31;
    const float4* yr = (const float4*)(y + (size_t)n * FF * CH + (size_t)f * CH);
    const float4* wr = (const float4*)(w1 + ((size_t)(f * CR + o)) * CH);
    float a = 0.f;
    #pragma unroll 8
    for (int j = 0; j < CH/4; ++j) {
        float4 yv = yr[j], wv = wr[j];
        a += yv.x*wv.x + yv.y*wv.y + yv.z*wv.z + yv.w*wv.w;
    }
    zl[t] = a > 0.f ? a : 0.f;                // zl[f*CR+o]
    __syncthreads();

    #pragma unroll
    for (int cc = 0; cc < 2; ++cc) {
        const int c = t + 256 * cc;
        const float4* w2r = (const float4*)(w2 + (size_t)c * FF * CR);
        const float4* zr  = (const float4*)zl;    // uniform index -> broadcast
        float b = 0.f;
        #pragma unroll 8
        for (int k = 0; k < FF*CR/4; ++k) {
            float4 wv = w2r[k], zv = zr[k];
            b += wv.x*zv.x + wv.y*zv.y + wv.z*zv.z + wv.w*zv.w;
        }
        s[(size_t)n * CH + c] = 1.f / (1.f + __expf(-b));
    }
}

// ---------------- Kernel 2: broadcast channel scale ----------------
// One wave per channel (94% lane util).  Nontemporal stores: out must not
// evict x (L3-resident since pool) before its second read.
__global__ void scale_kernel(const float* __restrict__ x,
                             const float* __restrict__ s,
                             float* __restrict__ out) {
    const int ch   = blockIdx.x * 4 + (threadIdx.x >> 6);  // n*CH + c
    const int lane = threadIdx.x & 63;
    const float sv = s[ch];
    const f4v* xb = (const f4v*)(x + (size_t)ch * HHW);
    f4v*       ob = (f4v*)(out + (size_t)ch * HHW);
    for (int i = lane; i < HW4; i += 64) {
        f4v v = xb[i] * sv;
        __builtin_nontemporal_store(v, ob + i);
    }
}

extern "C" void kernel_launch(void* const* d_in, const int* in_sizes, int n_in,
                              void* d_out, int out_size, void* d_ws, size_t ws_size,
                              hipStream_t stream) {
    const float* x   = (const float*)d_in[0];
    const float* dct = (const float*)d_in[1];
    const float* w1  = (const float*)d_in[2];
    const float* w2  = (const float*)d_in[3];
    float* out = (float*)d_out;

    float* y   = (float*)d_ws;                   // N*F*C = 512 KB
    float* s   = y + (size_t)NB * FF * CH;       // N*C   =  64 KB
    int*   cnt = (int*)(s + (size_t)NB * CH);    // N     = 128 B

    hipMemsetAsync(cnt, 0, NB * sizeof(int), stream);
    pool_excite_kernel<<<NB * BLKS_PER_N, 256, 0, stream>>>(x, dct, y, w1, w2, s, cnt);
    scale_kernel      <<<NB * (CH / 4),   256, 0, stream>>>(x, s, out);
}

// Round 4
// 419.044 us; speedup vs baseline: 2.1932x; 2.1932x over previous
//
#include <hip/hip_runtime.h>
#include <cstddef>

#define NB   32
#define CH   512
#define HHW  3136      // 56*56
#define HW4  784       // HHW/4
#define FF   8
#define CR   32        // C/R
#define CIT  2         // channels per wave in pool

typedef float f4v __attribute__((ext_vector_type(4)));

// ---------------- Kernel 1: separable multi-frequency DCT pooling ----------------
// FcaNet dct[f,h,w] = bu[U[f]](h) * bv[V[f]](w) (outer product; cos is even so
// freq -1 == freq 1).  Distinct bases p=0..3 <-> freq {0,1,2,3}.
//   sv_p = dot(bv_p[4w..], x[h,4w..]);  y[f] = sum bh[U[f]](h) * sv_{V[f]}
// U = [0,0,1,1,0,3,0,2], V = [0,1,0,1,3,0,2,0]
// Bases reconstructed from the dct input: row/col 0 of the right filters * sqrt(56).
// Lane = r*14 + wc: bv in registers (wc fixed per lane), bh via 4-addr LDS
// multicast.  One j-iteration loads 56 contiguous float4 = fully coalesced.
// NOTE (R2/R3 lessons, global): do NOT fuse excite via cross-block sync —
// per-block __threadfence costs ~650us in L2 writebacks on 8-XCD gfx950, and
// intra-kernel spin-wait hangs under rocprof dispatch replay.
__global__ __launch_bounds__(256, 4)
void pool_kernel(const float* __restrict__ x,
                 const float* __restrict__ dct,
                 float* __restrict__ y /* (N,F,C) */) {
    __shared__ float4 bht[60];      // [h] -> {b0,b1,b2,b3}(h); 56..59 zero pad
    __shared__ float4 bwt[14][4];   // [wc][p] -> b_p(4wc..4wc+3)

    const int t = threadIdx.x;
    const float SQ = 7.4833147735478827f;   // sqrt(56): b0(h) == 1/sqrt(56)
    if (t < 56) {
        bht[t] = make_float4(dct[0*HHW + t*56] * SQ,    // b0(h) from f0 (u=0)
                             dct[2*HHW + t*56] * SQ,    // b1(h) from f2 (u=1)
                             dct[7*HHW + t*56] * SQ,    // b2(h) from f7 (u=2)
                             dct[5*HHW + t*56] * SQ);   // b3(h) from f5 (u=3)
    } else if (t < 60) {
        bht[t] = make_float4(0.f, 0.f, 0.f, 0.f);       // pad for idle lanes
    } else if (t >= 64 && t < 120) {
        const int i = t - 64, wc = i >> 2, p = i & 3;
        const int FP[4] = {0, 1, 6, 4};                 // v=0,1,2,3 source filters
        const float4 v = *(const float4*)(dct + (size_t)FP[p]*HHW + wc*4);
        bwt[wc][p] = make_float4(v.x*SQ, v.y*SQ, v.z*SQ, v.w*SQ);
    }
    __syncthreads();

    const int lane = t & 63, wave = t >> 6;
    const int r  = lane / 14;                 // 0..3; 4 for lanes 56..63
    const int wc = lane % 14;
    const int lx = lane < 56 ? lane : 55;     // clamped in-bounds dup load
    const float zf = lane < 56 ? 1.f : 0.f;   // zero idle lanes' contributions
    float4 bw0 = bwt[wc][0], bw1 = bwt[wc][1], bw2 = bwt[wc][2], bw3 = bwt[wc][3];
    bw0.x*=zf; bw0.y*=zf; bw0.z*=zf; bw0.w*=zf;
    bw1.x*=zf; bw1.y*=zf; bw1.z*=zf; bw1.w*=zf;
    bw2.x*=zf; bw2.y*=zf; bw2.z*=zf; bw2.w*=zf;
    bw3.x*=zf; bw3.y*=zf; bw3.z*=zf; bw3.w*=zf;

    const int gc0 = blockIdx.x * (4*CIT) + wave * CIT;  // global channel base

    for (int it = 0; it < CIT; ++it) {
        const int gc = gc0 + it;                         // n*CH + c
        const float4* xb = (const float4*)(x + (size_t)gc * HHW);
        float acc[8] = {0.f,0.f,0.f,0.f,0.f,0.f,0.f,0.f};
        #pragma unroll
        for (int j = 0; j < 14; ++j) {                   // rows 4j..4j+3
            const float4 xv = xb[j*56 + lx];
            const float4 bh = bht[4*j + r];              // 4-addr multicast
            const float s0 = xv.x*bw0.x + xv.y*bw0.y + xv.z*bw0.z + xv.w*bw0.w;
            const float s1 = xv.x*bw1.x + xv.y*bw1.y + xv.z*bw1.z + xv.w*bw1.w;
            const float s2 = xv.x*bw2.x + xv.y*bw2.y + xv.z*bw2.z + xv.w*bw2.w;
            const float s3 = xv.x*bw3.x + xv.y*bw3.y + xv.z*bw3.z + xv.w*bw3.w;
            acc[0] += bh.x * s0;    // f0: (0,0)
            acc[1] += bh.x * s1;    // f1: (0,1)
            acc[2] += bh.y * s0;    // f2: (1,0)
            acc[3] += bh.y * s1;    // f3: (-1,-1) == (1,1)
            acc[4] += bh.x * s3;    // f4: (0,3)
            acc[5] += bh.w * s0;    // f5: (3,0)
            acc[6] += bh.x * s2;    // f6: (0,2)
            acc[7] += bh.z * s0;    // f7: (2,0)
        }

        // value-split butterfly over lane bits 0-2, then plain adds over 3-5
#define RSTEP(S, HALF)                                              \
        {                                                           \
            const bool hi = (lane >> (S)) & 1;                      \
            _Pragma("unroll")                                       \
            for (int k = 0; k < (HALF); ++k) {                      \
                float send = hi ? acc[k] : acc[k + (HALF)];         \
                float recv = __shfl_xor(send, 1 << (S), 64);        \
                acc[k] = (hi ? acc[k + (HALF)] : acc[k]) + recv;    \
            }                                                       \
        }
        RSTEP(0, 4) RSTEP(1, 2) RSTEP(2, 1)
#undef RSTEP
        acc[0] += __shfl_xor(acc[0], 8, 64);
        acc[0] += __shfl_xor(acc[0], 16, 64);
        acc[0] += __shfl_xor(acc[0], 32, 64);

        if (lane < 8) {
            const int f = ((lane & 1) << 2) | (lane & 2) | ((lane >> 2) & 1);
            y[(size_t)(gc >> 9) * (FF*CH) + (size_t)f * CH + (gc & (CH-1))] = acc[0];
        }
    }
}

// ---------------- Kernel 2: fused excite (z in LDS, one launch) ----------------
// Phase 1: thread (f,o) computes z[f,o] = relu(dot(y[n,f,:], w1[f,o,:]))  (256 dots)
// Phase 2: each thread 2 channels: s[c] = sigmoid(dot(z, w2[c,:,:]))
__global__ void excite_kernel(const float* __restrict__ y  /* (N,F,C)  */,
                              const float* __restrict__ w1 /* (F,CR,C) */,
                              const float* __restrict__ w2 /* (C,F,CR) */,
                              float* __restrict__ s        /* (N,C)    */) {
    const int n = blockIdx.x;
    __shared__ __align__(16) float zl[FF * CR];   // 1 KB

    const int f = threadIdx.x >> 5, o = threadIdx.x & 31;
    const float4* yr = (const float4*)(y + (size_t)n * FF * CH + (size_t)f * CH);
    const float4* wr = (const float4*)(w1 + ((size_t)(f * CR + o)) * CH);
    float a = 0.f;
    #pragma unroll 8
    for (int j = 0; j < CH/4; ++j) {
        float4 yv = yr[j], wv = wr[j];
        a += yv.x*wv.x + yv.y*wv.y + yv.z*wv.z + yv.w*wv.w;
    }
    zl[threadIdx.x] = a > 0.f ? a : 0.f;          // zl[f*CR+o]
    __syncthreads();

    #pragma unroll
    for (int cc = 0; cc < 2; ++cc) {
        const int c = threadIdx.x + 256 * cc;
        const float4* w2r = (const float4*)(w2 + (size_t)c * FF * CR);
        const float4* zr  = (const float4*)zl;    // uniform index -> broadcast
        float b = 0.f;
        #pragma unroll 8
        for (int k = 0; k < FF*CR/4; ++k) {
            float4 wv = w2r[k], zv = zr[k];
            b += wv.x*zv.x + wv.y*zv.y + wv.z*zv.z + wv.w*zv.w;
        }
        s[(size_t)n * CH + c] = 1.f / (1.f + __expf(-b));
    }
}

// ---------------- Kernel 3: broadcast channel scale ----------------
// One wave per channel (94% lane util).  Nontemporal stores for `out`:
// out-writes must not allocate in L3, so x (L3-resident since pool) keeps
// its hits for this second read.  x loads stay NORMAL (we want the L3 path).
__global__ void scale_kernel(const float* __restrict__ x,
                             const float* __restrict__ s,
                             float* __restrict__ out) {
    const int ch   = blockIdx.x * 4 + (threadIdx.x >> 6);  // n*CH + c
    const int lane = threadIdx.x & 63;
    const float sv = s[ch];
    const f4v* xb = (const f4v*)(x + (size_t)ch * HHW);
    f4v*       ob = (f4v*)(out + (size_t)ch * HHW);
    for (int i = lane; i < HW4; i += 64) {
        f4v v = xb[i] * sv;
        __builtin_nontemporal_store(v, ob + i);
    }
}

extern "C" void kernel_launch(void* const* d_in, const int* in_sizes, int n_in,
                              void* d_out, int out_size, void* d_ws, size_t ws_size,
                              hipStream_t stream) {
    const float* x   = (const float*)d_in[0];
    const float* dct = (const float*)d_in[1];
    const float* w1  = (const float*)d_in[2];
    const float* w2  = (const float*)d_in[3];
    float* out = (float*)d_out;

    float* y = (float*)d_ws;                     // N*F*C = 512 KB
    float* s = y + (size_t)NB * FF * CH;         // N*C   =  64 KB

    pool_kernel  <<<(NB*CH)/(4*CIT), 256, 0, stream>>>(x, dct, y);
    excite_kernel<<<NB,              256, 0, stream>>>(y, w1, w2, s);
    scale_kernel <<<NB * (CH / 4),   256, 0, stream>>>(x, s, out);
}

// Round 5
// 405.826 us; speedup vs baseline: 2.2646x; 1.0326x over previous
//
#include <hip/hip_runtime.h>
#include <cstddef>

#define NB   32
#define CH   512
#define HHW  3136      // 56*56
#define HW4  784       // HHW/4
#define FF   8
#define CR   32        // C/R
#define CIT  2         // channels per wave in pool

typedef float f4v __attribute__((ext_vector_type(4)));

// ---------------- Kernel 1: separable multi-frequency DCT pooling ----------------
// FcaNet dct[f,h,w] = bu[U[f]](h) * bv[V[f]](w) (outer product; cos is even so
// freq -1 == freq 1).  Distinct bases p=0..3 <-> freq {0,1,2,3}.
//   sv_p = dot(bv_p[4w..], x[h,4w..]);  y[f] = sum bh[U[f]](h) * sv_{V[f]}
// U = [0,0,1,1,0,3,0,2], V = [0,1,0,1,3,0,2,0]
// Lane = r*14 + wc: bv in registers (wc fixed per lane), bh via 4-addr LDS
// multicast.  One j-iteration loads 56 contiguous float4 = fully coalesced.
// NOTE (R2/R3 lessons, global): no cross-block sync fusion — per-block
// __threadfence costs ~650us in L2 writebacks on 8-XCD gfx950, and
// intra-kernel spin-wait hangs the harness under rocprof replay.
__global__ __launch_bounds__(256, 4)
void pool_kernel(const float* __restrict__ x,
                 const float* __restrict__ dct,
                 float* __restrict__ y /* (N,F,C) */) {
    __shared__ float4 bht[60];      // [h] -> {b0,b1,b2,b3}(h); 56..59 zero pad
    __shared__ float4 bwt[14][4];   // [wc][p] -> b_p(4wc..4wc+3)

    const int t = threadIdx.x;
    const float SQ = 7.4833147735478827f;   // sqrt(56): b0(h) == 1/sqrt(56)
    if (t < 56) {
        bht[t] = make_float4(dct[0*HHW + t*56] * SQ,    // b0(h) from f0 (u=0)
                             dct[2*HHW + t*56] * SQ,    // b1(h) from f2 (u=1)
                             dct[7*HHW + t*56] * SQ,    // b2(h) from f7 (u=2)
                             dct[5*HHW + t*56] * SQ);   // b3(h) from f5 (u=3)
    } else if (t < 60) {
        bht[t] = make_float4(0.f, 0.f, 0.f, 0.f);       // pad for idle lanes
    } else if (t >= 64 && t < 120) {
        const int i = t - 64, wc = i >> 2, p = i & 3;
        const int FP[4] = {0, 1, 6, 4};                 // v=0,1,2,3 source filters
        const float4 v = *(const float4*)(dct + (size_t)FP[p]*HHW + wc*4);
        bwt[wc][p] = make_float4(v.x*SQ, v.y*SQ, v.z*SQ, v.w*SQ);
    }
    __syncthreads();

    const int lane = t & 63, wave = t >> 6;
    const int r  = lane / 14;                 // 0..3; 4 for lanes 56..63
    const int wc = lane % 14;
    const int lx = lane < 56 ? lane : 55;     // clamped in-bounds dup load
    const float zf = lane < 56 ? 1.f : 0.f;   // zero idle lanes' contributions
    float4 bw0 = bwt[wc][0], bw1 = bwt[wc][1], bw2 = bwt[wc][2], bw3 = bwt[wc][3];
    bw0.x*=zf; bw0.y*=zf; bw0.z*=zf; bw0.w*=zf;
    bw1.x*=zf; bw1.y*=zf; bw1.z*=zf; bw1.w*=zf;
    bw2.x*=zf; bw2.y*=zf; bw2.z*=zf; bw2.w*=zf;
    bw3.x*=zf; bw3.y*=zf; bw3.z*=zf; bw3.w*=zf;

    const int gc0 = blockIdx.x * (4*CIT) + wave * CIT;  // global channel base

    for (int it = 0; it < CIT; ++it) {
        const int gc = gc0 + it;                         // n*CH + c
        const float4* xb = (const float4*)(x + (size_t)gc * HHW);
        float acc[8] = {0.f,0.f,0.f,0.f,0.f,0.f,0.f,0.f};
        #pragma unroll
        for (int j = 0; j < 14; ++j) {                   // rows 4j..4j+3
            const float4 xv = xb[j*56 + lx];
            const float4 bh = bht[4*j + r];              // 4-addr multicast
            const float s0 = xv.x*bw0.x + xv.y*bw0.y + xv.z*bw0.z + xv.w*bw0.w;
            const float s1 = xv.x*bw1.x + xv.y*bw1.y + xv.z*bw1.z + xv.w*bw1.w;
            const float s2 = xv.x*bw2.x + xv.y*bw2.y + xv.z*bw2.z + xv.w*bw2.w;
            const float s3 = xv.x*bw3.x + xv.y*bw3.y + xv.z*bw3.z + xv.w*bw3.w;
            acc[0] += bh.x * s0;    // f0: (0,0)
            acc[1] += bh.x * s1;    // f1: (0,1)
            acc[2] += bh.y * s0;    // f2: (1,0)
            acc[3] += bh.y * s1;    // f3: (-1,-1) == (1,1)
            acc[4] += bh.x * s3;    // f4: (0,3)
            acc[5] += bh.w * s0;    // f5: (3,0)
            acc[6] += bh.x * s2;    // f6: (0,2)
            acc[7] += bh.z * s0;    // f7: (2,0)
        }

        // value-split butterfly over lane bits 0-2, then plain adds over 3-5
#define RSTEP(S, HALF)                                              \
        {                                                           \
            const bool hi = (lane >> (S)) & 1;                      \
            _Pragma("unroll")                                       \
            for (int k = 0; k < (HALF); ++k) {                      \
                float send = hi ? acc[k] : acc[k + (HALF)];         \
                float recv = __shfl_xor(send, 1 << (S), 64);        \
                acc[k] = (hi ? acc[k + (HALF)] : acc[k]) + recv;    \
            }                                                       \
        }
        RSTEP(0, 4) RSTEP(1, 2) RSTEP(2, 1)
#undef RSTEP
        acc[0] += __shfl_xor(acc[0], 8, 64);
        acc[0] += __shfl_xor(acc[0], 16, 64);
        acc[0] += __shfl_xor(acc[0], 32, 64);

        if (lane < 8) {
            const int f = ((lane & 1) << 2) | (lane & 2) | ((lane >> 2) & 1);
            y[(size_t)(gc >> 9) * (FF*CH) + (size_t)f * CH + (gc & (CH-1))] = acc[0];
        }
    }
}

// ------------- Kernel 2: fused excite + scale (one launch, no s buffer) -------------
// 1024-thread blocks, 16 channels each (32 blocks per n).  Each block
// recomputes z for its n from LDS-staged y (redundancy cost: 512 KB of
// L2-resident w1 per block x 1024 blocks = 15 us aggregate L2 traffic —
// cheap vs a separate 32-block excite kernel launch + s round-trip).
// Phase A: stage y[n] (16 KB) to LDS.
// Phase B: z[fo] = relu(dot(y[n,f,:], w1[fo,:])), 4 threads per fo
//          (64B-line coalesced w1, broadcast yl reads), quad shuffle-reduce.
// Phase C: wave w owns channel cb*16+w: s = sigmoid(dot(zl, w2[c])) via
//          per-lane float4 partial + full butterfly; then stream x*s -> out
//          with PLAIN stores (fills prove plain stores hit 6.6 TB/s here;
//          testing whether R1's nontemporal stores were throttling scale).
__global__ __launch_bounds__(1024, 8)
void excite_scale_kernel(const float* __restrict__ x,
                         const float* __restrict__ y  /* (N,F,C)  */,
                         const float* __restrict__ w1 /* (F,CR,C) */,
                         const float* __restrict__ w2 /* (C,F,CR) */,
                         float* __restrict__ out) {
    const int n  = blockIdx.x >> 5;          // 32 blocks per n
    const int cb = blockIdx.x & 31;          // 16-channel group within n
    const int t  = threadIdx.x;

    __shared__ __align__(16) float yl[FF * CH];   // 16 KB
    __shared__ __align__(16) float zl[FF * CR];   // 1 KB

    // Phase A: y[n] -> LDS (one float4 per thread, fully coalesced)
    ((float4*)yl)[t] = ((const float4*)(y + (size_t)n * FF * CH))[t];
    __syncthreads();

    // Phase B: z, 4 threads per output (fo = f*32+o)
    {
        const int fo = t >> 2, p = t & 3;
        const float4* yr = (const float4*)yl + (size_t)(fo >> 5) * (CH/4);
        const float4* wr = (const float4*)(w1 + (size_t)fo * CH);
        float a = 0.f;
        #pragma unroll 8
        for (int j = 0; j < 32; ++j) {           // p covers float4s {p, p+4, ...}
            const float4 yv = yr[p + 4*j];       // same-addr 16-way broadcast
            const float4 wv = wr[p + 4*j];       // 64B line per lane-quad
            a += yv.x*wv.x + yv.y*wv.y + yv.z*wv.z + yv.w*wv.w;
        }
        a += __shfl_xor(a, 1, 64);
        a += __shfl_xor(a, 2, 64);
        if (p == 0) zl[fo] = a > 0.f ? a : 0.f;
    }
    __syncthreads();

    // Phase C: one wave per channel
    const int w = t >> 6, lane = t & 63;
    const int c = cb * 16 + w;                   // channel within n
    const float4 zv = ((const float4*)zl)[lane];                       // 256 floats = 64 f4
    const float4 wv = ((const float4*)(w2 + (size_t)c * FF * CR))[lane];
    float a = zv.x*wv.x + zv.y*wv.y + zv.z*wv.z + zv.w*wv.w;
    a += __shfl_xor(a, 1, 64);
    a += __shfl_xor(a, 2, 64);
    a += __shfl_xor(a, 4, 64);
    a += __shfl_xor(a, 8, 64);
    a += __shfl_xor(a, 16, 64);
    a += __shfl_xor(a, 32, 64);
    const float sv = 1.f / (1.f + __expf(-a));   // all lanes hold s[c]

    const int ch = n * CH + c;
    const float4* xb = (const float4*)(x + (size_t)ch * HHW);
    float4*       ob = (float4*)(out + (size_t)ch * HHW);
    for (int i = lane; i < HW4; i += 64) {
        float4 v = xb[i];
        v.x *= sv; v.y *= sv; v.z *= sv; v.w *= sv;
        ob[i] = v;
    }
}

extern "C" void kernel_launch(void* const* d_in, const int* in_sizes, int n_in,
                              void* d_out, int out_size, void* d_ws, size_t ws_size,
                              hipStream_t stream) {
    const float* x   = (const float*)d_in[0];
    const float* dct = (const float*)d_in[1];
    const float* w1  = (const float*)d_in[2];
    const float* w2  = (const float*)d_in[3];
    float* out = (float*)d_out;

    float* y = (float*)d_ws;                     // N*F*C = 512 KB

    pool_kernel        <<<(NB*CH)/(4*CIT), 256,  0, stream>>>(x, dct, y);
    excite_scale_kernel<<<NB * 32,         1024, 0, stream>>>(x, y, w1, w2, out);
}